// Round 1
// baseline (4397.029 us; speedup 1.0000x reference)
//
#include <hip/hip_runtime.h>

// ARIMA flow-sampling: x_{k+1} = x_k + (MLP([x_k, t_k]) - noise) * dt, 100 steps.
// B=1024, Q=96, C=16, H=100. Rows = (b,c) pairs: M = 16384 independent rows.
// Persistent kernel: 256 WGs x 512 threads, each WG owns 64 rows for all 100
// steps. State lives in LDS transposed [feature][row] (lane = row -> conflict-
// free ds_read_b32, 2 lanes/bank). Neuron index is wave-uniform -> weights are
// SGPR broadcasts (s_load) via readfirstlane; inner loop is v_fmac v,s,v.

#define NB 1024
#define NQ 96
#define NC 16
#define NH 100
#define NSTEPS_ 100
#define QP1 97   // Q+1: state features
#define QP2 98   // Q+2: W1 row stride (feature 97 = t)
#define ROWS 64  // rows per workgroup
#define NTHR 512 // 8 waves

__device__ __forceinline__ float fast_tanh(float x) {
  // tanh(x) = 1 - 2/(exp2(2*log2e*x)+1); exact at +-inf saturation.
  float e = __builtin_amdgcn_exp2f(x * 2.88539008177792681f);
  float r = __builtin_amdgcn_rcpf(e + 1.0f);
  return fmaf(-2.0f, r, 1.0f);
}

// One pass: each wave computes J neurons j = w + 8*(i0+jj) for its 64 rows.
// src: LDS [K][ROWS]. W row-major stride WS. HAS_T folds t*W[j][K] into bias.
// UPDATE: dst (=xs) += (acc - ns)*dt  instead of writing tanh to dst.
template <int J, int K, int WS, bool HAS_T, bool UPDATE>
__device__ __forceinline__ void mlp_pass(const float* __restrict__ W,
                                         const float* __restrict__ bias,
                                         const float* src, float* dst,
                                         const float* nsv, int w, int r, int i0,
                                         float t, int jlim) {
  float acc[J];
  int jo[J], jv[J];
#pragma unroll
  for (int jj = 0; jj < J; ++jj) {
    int j = w + 8 * (i0 + jj);
    jv[jj] = j;
    int jc = (j < jlim) ? j : (jlim - 1);      // clamp tail (guarded on write)
    jc = __builtin_amdgcn_readfirstlane(jc);   // force wave-uniform -> s_load
    jo[jj] = jc * WS;
    float a = bias[jc];
    if constexpr (HAS_T) a = fmaf(t, W[jo[jj] + K], a);
    acc[jj] = a;
  }
#pragma unroll 4
  for (int k = 0; k < K; ++k) {
    float xk = src[k * ROWS + r];  // 64 consecutive dwords: conflict-free
#pragma unroll
    for (int jj = 0; jj < J; ++jj)
      acc[jj] = fmaf(xk, W[jo[jj] + k], acc[jj]);  // weight is SGPR broadcast
  }
  const float dt = 1.0f / (float)NSTEPS_;
#pragma unroll
  for (int jj = 0; jj < J; ++jj) {
    int j = jv[jj];
    if (j < jlim) {
      int o = j * ROWS + r;
      if constexpr (UPDATE) {
        dst[o] = fmaf(acc[jj] - nsv[o], dt, dst[o]);
      } else {
        dst[o] = fast_tanh(acc[jj]);
      }
    }
  }
}

__global__ void __launch_bounds__(NTHR, 1)
arima_flow_kernel(const float* __restrict__ series,
                  const float* __restrict__ rand_error,
                  const float* __restrict__ W1, const float* __restrict__ b1,
                  const float* __restrict__ W2, const float* __restrict__ b2,
                  const float* __restrict__ W3, const float* __restrict__ b3,
                  float* __restrict__ out) {
  // 100,864 B static LDS (gfx950 allows 160 KB/WG) -> 1 WG/CU, 8 waves.
  __shared__ float xs[QP1 * ROWS];  // state x, transposed [q][row]
  __shared__ float ns[QP1 * ROWS];  // initial noise (constant)
  __shared__ float ha[NH * ROWS];   // h1
  __shared__ float hb[NH * ROWS];   // h2

  const int tid = threadIdx.x;
  const int w = tid >> 6;   // wave id 0..7 = neuron slot
  const int r = tid & 63;   // lane = row within tile
  const int m0 = blockIdx.x * ROWS;

  // Load initial state: row m = b*16+c, x[q] = series[b,q,c]; x[96] = rand_error.
  for (int idx = tid; idx < NQ * ROWS; idx += NTHR) {
    int q = idx >> 6, rr = idx & 63;
    int m = m0 + rr;
    int b = m >> 4, c = m & 15;
    float v = series[(b * NQ + q) * NC + c];
    xs[q * ROWS + rr] = v;
    ns[q * ROWS + rr] = v;
  }
  if (tid < ROWS) {
    float v = rand_error[m0 + tid];
    xs[NQ * ROWS + tid] = v;
    ns[NQ * ROWS + tid] = v;
  }
  __syncthreads();

  for (int step = 0; step < NSTEPS_; ++step) {
    float t = (float)step / (float)NSTEPS_;  // matches ref: i(f32) / 100
    // layer 1: h1 = tanh(x @ W1[:, :97]^T + t*W1[:,97] + b1)
    mlp_pass<8, QP1, QP2, true, false>(W1, b1, xs, ha, nullptr, w, r, 0, t, NH);
    mlp_pass<5, QP1, QP2, true, false>(W1, b1, xs, ha, nullptr, w, r, 8, t, NH);
    __syncthreads();
    // layer 2: h2 = tanh(h1 @ W2^T + b2)
    mlp_pass<8, NH, NH, false, false>(W2, b2, ha, hb, nullptr, w, r, 0, t, NH);
    mlp_pass<5, NH, NH, false, false>(W2, b2, ha, hb, nullptr, w, r, 8, t, NH);
    __syncthreads();
    // layer 3 + Euler update: x[n] += (h2 @ W3[n]^T + b3[n] - noise[n]) * dt
    mlp_pass<8, NH, NH, false, true>(W3, b3, hb, xs, ns, w, r, 0, t, QP1);
    mlp_pass<5, NH, NH, false, true>(W3, b3, hb, xs, ns, w, r, 8, t, QP1);
    __syncthreads();
  }

  // Store x -> out (B, 97, 16) f32.
  for (int idx = tid; idx < QP1 * ROWS; idx += NTHR) {
    int q = idx >> 6, rr = idx & 63;
    int m = m0 + rr;
    int b = m >> 4, c = m & 15;
    out[(b * QP1 + q) * NC + c] = xs[q * ROWS + rr];
  }
}

extern "C" void kernel_launch(void* const* d_in, const int* in_sizes, int n_in,
                              void* d_out, int out_size, void* d_ws,
                              size_t ws_size, hipStream_t stream) {
  const float* series = (const float*)d_in[0];
  const float* rand_error = (const float*)d_in[1];
  const float* W1 = (const float*)d_in[2];
  const float* b1 = (const float*)d_in[3];
  const float* W2 = (const float*)d_in[4];
  const float* b2 = (const float*)d_in[5];
  const float* W3 = (const float*)d_in[6];
  const float* b3 = (const float*)d_in[7];
  float* out = (float*)d_out;

  dim3 grid((NB * NC) / ROWS);  // 256 WGs = 1 per CU (LDS-limited anyway)
  dim3 block(NTHR);
  hipLaunchKernelGGL(arima_flow_kernel, grid, block, 0, stream, series,
                     rand_error, W1, b1, W2, b2, W3, b3, out);
}

// Round 2
// 338.041 us; speedup vs baseline: 13.0074x; 13.0074x over previous
//
#include <hip/hip_runtime.h>

// ARIMA flow sampling via bf16 MFMA. B=1024,Q=96,C=16,H=100, 100 Euler steps.
// 16384 rows (b,c). 256 WGs x 512 thr; WG owns 64 rows for all 100 steps.
// Per step: 3 GEMMs (64 x ~100 x ~100) with mfma_f32_16x16x32_bf16.
//   - Weights live in VGPRs as B-frags, loaded ONCE (96 VGPRs/wave). No SMEM
//     and no weight LDS traffic in the hot loop (R1 lesson: s_load in the
//     k-loop forces lgkmcnt(0) drains of all ds_reads -> 21% VALUBusy).
//   - Activations in LDS bf16 [row][feat], stride 136 (16B-aligned rows,
//     conflict-free ds_read_b128 A-frags).
//   - x master state + noise stay fp32 in owner-wave D-frag registers; only
//     the bf16 copy used as next-step A input is rounded.
// Wave tiling: 8 waves = 2 m-groups x 4 n-groups; each wave 2x2 tiles of 16.
// Frag layouts (verified, guide S3): A[m=lane&15][k=quad*8+j] (8 contig bf16
// = b128 from [row][feat]); B from W[n][k] row-major, n=lane&15, k=quad*8+j;
// C/D: col(n)=lane&15, row(m)=quad*4+reg.

#define NB 1024
#define NQ 96
#define NC 16
#define NH 100
#define QP1 97
#define QP2 98
#define NSTEPS_ 100
#define ROWS 64
#define NTHR 512
#define STR 136  // bf16 elems per activation row (pad: rows 16B-aligned)

typedef __attribute__((ext_vector_type(8))) short bf16x8;
typedef __attribute__((ext_vector_type(4))) float f32x4;

__device__ __forceinline__ short f2bf(float f) {  // RNE f32 -> bf16
  unsigned u = __builtin_bit_cast(unsigned, f);
  u = u + 0x7fffu + ((u >> 16) & 1u);
  return (short)(u >> 16);
}

__device__ __forceinline__ float fast_tanh(float x) {
  float e = __builtin_amdgcn_exp2f(x * 2.88539008177792681f);
  float r = __builtin_amdgcn_rcpf(e + 1.0f);
  return fmaf(-2.0f, r, 1.0f);
}

// Load one wave-slot's B-frags for one layer: W row-major [nrows][ws],
// valid k < kvalid, zero-padded to 128. n is this lane's output column.
__device__ __forceinline__ void load_bf(const float* __restrict__ W, int ws,
                                        int nrows, int kvalid, int n, int quad,
                                        bf16x8 dst[4]) {
#pragma unroll
  for (int kb = 0; kb < 4; ++kb) {
    bf16x8 v;
    int k0 = kb * 32 + quad * 8;
#pragma unroll
    for (int i = 0; i < 8; ++i) {
      int k = k0 + i;
      float f = (n < nrows && k < kvalid) ? W[n * ws + k] : 0.0f;
      v[i] = f2bf(f);
    }
    dst[kb] = v;
  }
}

// 2x2 tile GEMM: acc[mtl][ntl] += A(src) * B(bf). aoff = lane's A byte... (shorts).
__device__ __forceinline__ void gemm22(const short* __restrict__ src, int aoff,
                                       const bf16x8 (&bf)[2][4],
                                       f32x4 (&acc)[2][2]) {
#pragma unroll
  for (int kb = 0; kb < 4; ++kb) {
    bf16x8 a0 = *(const bf16x8*)(src + aoff + kb * 32);
    bf16x8 a1 = *(const bf16x8*)(src + aoff + 16 * STR + kb * 32);
    acc[0][0] = __builtin_amdgcn_mfma_f32_16x16x32_bf16(a0, bf[0][kb], acc[0][0], 0, 0, 0);
    acc[0][1] = __builtin_amdgcn_mfma_f32_16x16x32_bf16(a0, bf[1][kb], acc[0][1], 0, 0, 0);
    acc[1][0] = __builtin_amdgcn_mfma_f32_16x16x32_bf16(a1, bf[0][kb], acc[1][0], 0, 0, 0);
    acc[1][1] = __builtin_amdgcn_mfma_f32_16x16x32_bf16(a1, bf[1][kb], acc[1][1], 0, 0, 0);
  }
}

__device__ __forceinline__ void store_tanh(short* __restrict__ dst, int mt0,
                                           int nt0, int col, int quad,
                                           f32x4 (&acc)[2][2], int nvalid) {
#pragma unroll
  for (int mtl = 0; mtl < 2; ++mtl)
#pragma unroll
    for (int ntl = 0; ntl < 2; ++ntl) {
      int n = (nt0 + ntl) * 16 + col;
      if (n < nvalid) {
        int base = ((mt0 + mtl) * 16 + quad * 4) * STR + n;
#pragma unroll
        for (int reg = 0; reg < 4; ++reg)
          dst[base + reg * STR] = f2bf(fast_tanh(acc[mtl][ntl][reg]));
      }
    }
}

__global__ void __launch_bounds__(NTHR, 2)
arima_mfma_kernel(const float* __restrict__ series,
                  const float* __restrict__ rand_error,
                  const float* __restrict__ W1, const float* __restrict__ b1,
                  const float* __restrict__ W2, const float* __restrict__ b2,
                  const float* __restrict__ W3, const float* __restrict__ b3,
                  float* __restrict__ out) {
  __shared__ short bufP[ROWS * STR];
  __shared__ short bufQ[ROWS * STR];

  const int tid = threadIdx.x;
  const int w = tid >> 6, l = tid & 63;
  const int col = l & 15, quad = l >> 4;
  const int mt0 = (w >> 2) * 2, nt0 = (w & 3) * 2;
  const int m0 = blockIdx.x * ROWS;

  // Zero both buffers: pad regions (k>=valid) must be 0 or finite-stale only;
  // B-frag zero padding then kills any stale-but-finite values.
  {
    int* zp = (int*)bufP;
    int* zq = (int*)bufQ;
    for (int i = tid; i < ROWS * STR / 2; i += NTHR) { zp[i] = 0; zq[i] = 0; }
  }

  // ---- one-time: weights -> VGPR B-frags (bf16), biases -> VGPRs ----
  bf16x8 bfr[3][2][4];
  float biasf[3][2], w97f[2];
#pragma unroll
  for (int ntl = 0; ntl < 2; ++ntl) {
    int n = (nt0 + ntl) * 16 + col;
    load_bf(W1, QP2, NH, QP1, n, quad, bfr[0][ntl]);  // k<97; k=97 is t col
    load_bf(W2, NH, NH, NH, n, quad, bfr[1][ntl]);
    load_bf(W3, NH, QP1, NH, n, quad, bfr[2][ntl]);
    biasf[0][ntl] = (n < NH) ? b1[n] : 0.0f;
    biasf[1][ntl] = (n < NH) ? b2[n] : 0.0f;
    biasf[2][ntl] = (n < QP1) ? b3[n] : 0.0f;
    w97f[ntl] = (n < NH) ? W1[n * QP2 + QP1] : 0.0f;  // t column, folded in bias
  }

  // ---- one-time: x0 / noise -> fp32 D-frag registers (owner wave) ----
  f32x4 xm[2][2], nsv[2][2];
#pragma unroll
  for (int mtl = 0; mtl < 2; ++mtl)
#pragma unroll
    for (int ntl = 0; ntl < 2; ++ntl) {
      int q = (nt0 + ntl) * 16 + col;
      f32x4 v;
#pragma unroll
      for (int reg = 0; reg < 4; ++reg) {
        int m = (mt0 + mtl) * 16 + quad * 4 + reg;
        int row = m0 + m;
        float f = 0.0f;
        if (q < NQ) f = series[((row >> 4) * NQ + q) * NC + (row & 15)];
        else if (q == NQ) f = rand_error[row];
        v[reg] = f;
      }
      xm[mtl][ntl] = v;
      nsv[mtl][ntl] = v;
    }

  __syncthreads();  // zeroing done before x writes

  // write x0 (bf16) into bufP
#pragma unroll
  for (int mtl = 0; mtl < 2; ++mtl)
#pragma unroll
    for (int ntl = 0; ntl < 2; ++ntl) {
      int n = (nt0 + ntl) * 16 + col;
      if (n < QP1) {
        int base = ((mt0 + mtl) * 16 + quad * 4) * STR + n;
#pragma unroll
        for (int reg = 0; reg < 4; ++reg)
          bufP[base + reg * STR] = f2bf(xm[mtl][ntl][reg]);
      }
    }
  __syncthreads();

  const int aoff = (mt0 * 16 + col) * STR + quad * 8;  // A-frag base (shorts)
  short* bx = bufP;  // holds x at step start
  short* bh = bufQ;

  for (int step = 0; step < NSTEPS_; ++step) {
    float t = (float)step / 100.0f;
    f32x4 acc[2][2];

    // L1: h1 = tanh(x @ W1[:, :97]^T + t*W1[:,97] + b1); read bx -> write bh
#pragma unroll
    for (int mtl = 0; mtl < 2; ++mtl)
#pragma unroll
      for (int ntl = 0; ntl < 2; ++ntl) {
        float bv = fmaf(t, w97f[ntl], biasf[0][ntl]);
        acc[mtl][ntl] = {bv, bv, bv, bv};
      }
    gemm22(bx, aoff, bfr[0], acc);
    store_tanh(bh, mt0, nt0, col, quad, acc, NH);
    __syncthreads();

    // L2: h2 = tanh(h1 @ W2^T + b2); read bh -> write bx (x dead after L1)
#pragma unroll
    for (int mtl = 0; mtl < 2; ++mtl)
#pragma unroll
      for (int ntl = 0; ntl < 2; ++ntl) {
        float bv = biasf[1][ntl];
        acc[mtl][ntl] = {bv, bv, bv, bv};
      }
    gemm22(bh, aoff, bfr[1], acc);
    store_tanh(bx, mt0, nt0, col, quad, acc, NH);
    __syncthreads();

    // L3: pred = h2 @ W3^T + b3; x += (pred - noise)*dt; write new x -> bh
#pragma unroll
    for (int mtl = 0; mtl < 2; ++mtl)
#pragma unroll
      for (int ntl = 0; ntl < 2; ++ntl) {
        float bv = biasf[2][ntl];
        acc[mtl][ntl] = {bv, bv, bv, bv};
      }
    gemm22(bx, aoff, bfr[2], acc);
#pragma unroll
    for (int mtl = 0; mtl < 2; ++mtl)
#pragma unroll
      for (int ntl = 0; ntl < 2; ++ntl) {
#pragma unroll
        for (int reg = 0; reg < 4; ++reg)
          xm[mtl][ntl][reg] = fmaf(acc[mtl][ntl][reg] - nsv[mtl][ntl][reg],
                                   0.01f, xm[mtl][ntl][reg]);
        int n = (nt0 + ntl) * 16 + col;
        if (n < QP1) {
          int base = ((mt0 + mtl) * 16 + quad * 4) * STR + n;
#pragma unroll
          for (int reg = 0; reg < 4; ++reg)
            bh[base + reg * STR] = f2bf(xm[mtl][ntl][reg]);
        }
      }
    __syncthreads();

    short* tp = bx;  // swap: new x is in bh
    bx = bh;
    bh = tp;
  }

  // final store: x master frags (fp32) -> out (B, 97, 16)
#pragma unroll
  for (int mtl = 0; mtl < 2; ++mtl)
#pragma unroll
    for (int ntl = 0; ntl < 2; ++ntl) {
      int q = (nt0 + ntl) * 16 + col;
      if (q < QP1) {
#pragma unroll
        for (int reg = 0; reg < 4; ++reg) {
          int m = (mt0 + mtl) * 16 + quad * 4 + reg;
          int row = m0 + m;
          out[((row >> 4) * QP1 + q) * NC + (row & 15)] = xm[mtl][ntl][reg];
        }
      }
    }
}

extern "C" void kernel_launch(void* const* d_in, const int* in_sizes, int n_in,
                              void* d_out, int out_size, void* d_ws,
                              size_t ws_size, hipStream_t stream) {
  const float* series = (const float*)d_in[0];
  const float* rand_error = (const float*)d_in[1];
  const float* W1 = (const float*)d_in[2];
  const float* b1 = (const float*)d_in[3];
  const float* W2 = (const float*)d_in[4];
  const float* b2 = (const float*)d_in[5];
  const float* W3 = (const float*)d_in[6];
  const float* b3 = (const float*)d_in[7];
  float* out = (float*)d_out;

  dim3 grid((NB * NC) / ROWS);  // 256 WGs
  dim3 block(NTHR);
  hipLaunchKernelGGL(arima_mfma_kernel, grid, block, 0, stream, series,
                     rand_error, W1, b1, W2, b2, W3, b3, out);
}

// Round 3
// 290.133 us; speedup vs baseline: 15.1552x; 1.1651x over previous
//
#include <hip/hip_runtime.h>

// ARIMA flow sampling, transposed-MFMA version. B=1024,Q=96,C=16,H=100,100 steps.
// Grid 1024 WGs (= batch index), 256 thr (4 waves), WG owns 16 rows (channels).
// Transposed GEMM: A = weights (m=neuron, in VGPRs, loaded once),
//                  B = activations (n=data row, LDS [row][feat] bf16, STR=136).
// D layout: col=lane&15 -> data row, row=quad*4+reg -> neuron => each lane's 4
// regs are CONTIGUOUS feats -> pack to one ds_write_b64 (conflict-free, 4x
// fewer write instrs than R2's b16 scatter which was 4-way bank-conflicted).
// Bias + t are folded into the GEMM as extra input features:
//   x-row: feat 97 = t, feat 98 = 1.0 ; h-row: feat 100 = 1.0
//   A-frags: k<KW -> W[m][k], k==KW -> bias[m], else 0  (zero acc init, no
//   bias registers). Invalid neurons have all-zero A rows -> exact 0 outputs.
// x master state + noise stay fp32 in owner-lane registers.

#define NB 1024
#define NQ 96
#define NC 16
#define NH 100
#define QP1 97
#define QP2 98
#define ROWS 16
#define NTHR 256
#define STR 136  // shorts per LDS row; 16B-aligned, reads 8-lane/bank-group opt
#define NSTEPS_ 100

typedef __attribute__((ext_vector_type(8))) short bf16x8;
typedef __attribute__((ext_vector_type(4))) float f32x4;
typedef __attribute__((ext_vector_type(2))) unsigned uintx2;

__device__ __forceinline__ short f2bf_rne(float f) {  // one-time loads only
  unsigned u = __builtin_bit_cast(unsigned, f);
  u = u + 0x7fffu + ((u >> 16) & 1u);
  return (short)(u >> 16);
}

__device__ __forceinline__ unsigned bfhi(float f) {  // round-half-up bf16 bits
  return (__builtin_bit_cast(unsigned, f) + 0x8000u) >> 16;
}

// pack two half-up-rounded bf16 into one dword: lo=bf(a), hi=bf(b). 2 add+1 perm.
__device__ __forceinline__ unsigned pack_bf2(float a, float b) {
  unsigned ua = __builtin_bit_cast(unsigned, a) + 0x8000u;
  unsigned ub = __builtin_bit_cast(unsigned, b) + 0x8000u;
  return __builtin_amdgcn_perm(ub, ua, 0x07060302);
}

__device__ __forceinline__ float fast_tanh(float x) {
  float e = __builtin_amdgcn_exp2f(x * 2.88539008177792681f);
  float r = __builtin_amdgcn_rcpf(e + 1.0f);
  return fmaf(-2.0f, r, 1.0f);
}

// Weight A-frag: lane holds W'[m][k], m=(tile*16 + lane&15), k=kb*32+quad*8+j.
// W' = [W | bias], zero-padded to k<128 and m<16*tiles.
__device__ void load_afrag(const float* __restrict__ W,
                           const float* __restrict__ bias, int ws, int mvalid,
                           int KW, int m, int quad, bf16x8 dst[4]) {
#pragma unroll
  for (int kb = 0; kb < 4; ++kb) {
    bf16x8 v;
#pragma unroll
    for (int i = 0; i < 8; ++i) {
      int k = kb * 32 + quad * 8 + i;
      float f = 0.0f;
      if (m < mvalid) {
        if (k < KW) f = W[m * ws + k];
        else if (k == KW) f = bias[m];
      }
      v[i] = f2bf_rne(f);
    }
    dst[kb] = v;
  }
}

// acc[mtl] = sum_k A[mtl]*B ; B-frags read from LDS [row][feat].
__device__ __forceinline__ void gemm2(const short* __restrict__ src, int rbase,
                                      const bf16x8 (&A)[2][4], f32x4 (&acc)[2]) {
  acc[0] = {0.0f, 0.0f, 0.0f, 0.0f};
  acc[1] = {0.0f, 0.0f, 0.0f, 0.0f};
#pragma unroll
  for (int kb = 0; kb < 4; ++kb) {
    bf16x8 bv = *(const bf16x8*)(src + rbase + kb * 32);  // 16B aligned
    acc[0] = __builtin_amdgcn_mfma_f32_16x16x32_bf16(A[0][kb], bv, acc[0], 0, 0, 0);
    acc[1] = __builtin_amdgcn_mfma_f32_16x16x32_bf16(A[1][kb], bv, acc[1], 0, 0, 0);
  }
}

// tanh + pack + single b64 store per m-tile. fix100: force feat 100 = 1.0.
__device__ __forceinline__ void store_h(short* __restrict__ dst, int wb0,
                                        int wb1, bool fix100, f32x4 (&acc)[2]) {
#pragma unroll
  for (int mtl = 0; mtl < 2; ++mtl) {
    unsigned u0 = pack_bf2(fast_tanh(acc[mtl][0]), fast_tanh(acc[mtl][1]));
    unsigned u1 = pack_bf2(fast_tanh(acc[mtl][2]), fast_tanh(acc[mtl][3]));
    if (mtl == 0 && fix100) u0 = (u0 & 0xFFFF0000u) | 0x3F80u;  // bf16(1.0)
    uintx2 v;
    v.x = u0;
    v.y = u1;
    *(uintx2*)(dst + (mtl ? wb1 : wb0)) = v;
  }
}

// write x master (+ t at feat 97, 1.0 at feat 98) as bf16.
__device__ __forceinline__ void write_x(short* __restrict__ dst, int wb0,
                                        int wb1, bool fix96, unsigned tbits,
                                        f32x4 (&xm)[2]) {
#pragma unroll
  for (int mtl = 0; mtl < 2; ++mtl) {
    unsigned u0 = pack_bf2(xm[mtl][0], xm[mtl][1]);
    unsigned u1 = pack_bf2(xm[mtl][2], xm[mtl][3]);
    if (mtl == 0 && fix96) {          // feats 96..99 = [x96, t, 1.0, 0]
      u0 = (u0 & 0x0000FFFFu) | (tbits << 16);
      u1 = 0x00003F80u;
    }
    uintx2 v;
    v.x = u0;
    v.y = u1;
    *(uintx2*)(dst + (mtl ? wb1 : wb0)) = v;
  }
}

__global__ void __launch_bounds__(NTHR, 3)
arima_mfma_t(const float* __restrict__ series,
             const float* __restrict__ rand_error,
             const float* __restrict__ W1, const float* __restrict__ b1,
             const float* __restrict__ W2, const float* __restrict__ b2,
             const float* __restrict__ W3, const float* __restrict__ b3,
             float* __restrict__ out) {
  __shared__ __align__(16) short bufP[ROWS * STR];
  __shared__ __align__(16) short bufQ[ROWS * STR];

  const int tid = threadIdx.x;
  const int w = tid >> 6, l = tid & 63;
  const int col = l & 15, quad = l >> 4;  // col = channel = data row in tile
  const int mt0 = 2 * w;                  // wave owns m-tiles 2w, 2w+1
  const int bglob = (int)blockIdx.x;      // ROWS == NC == 16: WG = one batch b

  // ---- one-time: weights (+bias/t cols) -> A-frags in VGPRs ----
  bf16x8 afr[3][2][4];
#pragma unroll
  for (int mtl = 0; mtl < 2; ++mtl) {
    int m = (mt0 + mtl) * 16 + col;
    load_afrag(W1, b1, QP2, NH, QP2, m, quad, afr[0][mtl]);   // k<98: W1 (incl t col), 98: b1
    load_afrag(W2, b2, NH, NH, NH, m, quad, afr[1][mtl]);     // k<100: W2, 100: b2
    load_afrag(W3, b3, NH, QP1, NH, m, quad, afr[2][mtl]);    // m<97 rows only
  }

  // ---- one-time: x0 / noise -> fp32 owner-lane registers ----
  f32x4 xm[2], ns[2];
#pragma unroll
  for (int mtl = 0; mtl < 2; ++mtl)
#pragma unroll
    for (int r = 0; r < 4; ++r) {
      int q = (mt0 + mtl) * 16 + quad * 4 + r;
      float f = 0.0f;
      if (q < NQ) f = series[(bglob * NQ + q) * NC + col];
      else if (q == NQ) f = rand_error[bglob * NC + col];
      xm[mtl][r] = f;
      ns[mtl][r] = f;
    }

  const int wb0 = col * STR + (mt0 + 0) * 16 + quad * 4;  // b64 dest (shorts)
  const int wb1 = col * STR + (mt0 + 1) * 16 + quad * 4;
  const int base0 = (mt0 + 0) * 16 + quad * 4;
  const bool fix100 = (base0 == 100);  // h feat 100 = 1.0 (bias input)
  const bool fix96 = (base0 == 96);    // x feats 97,98 = t, 1.0
  const int rbase = col * STR + quad * 8;  // B-frag read base (shorts)

  write_x(bufP, wb0, wb1, fix96, 0u /*t=0*/, xm);
  __syncthreads();

  short* bx = bufP;
  short* bh = bufQ;

#pragma unroll 1
  for (int step = 0; step < NSTEPS_; ++step) {
    f32x4 acc[2];
    // L1: h1 = tanh([x,t,1] @ W1'^T)   read bx -> write bh
    gemm2(bx, rbase, afr[0], acc);
    store_h(bh, wb0, wb1, fix100, acc);
    __syncthreads();
    // L2: h2 = tanh([h1,1] @ W2'^T)    read bh -> write bx
    gemm2(bh, rbase, afr[1], acc);
    store_h(bx, wb0, wb1, fix100, acc);
    __syncthreads();
    // L3: pred = [h2,1] @ W3'^T ; x += (pred - noise)*dt ; write new x -> bh
    gemm2(bx, rbase, afr[2], acc);
#pragma unroll
    for (int mtl = 0; mtl < 2; ++mtl)
#pragma unroll
      for (int r = 0; r < 4; ++r)
        xm[mtl][r] = fmaf(acc[mtl][r] - ns[mtl][r], 0.01f, xm[mtl][r]);
    float t1 = (float)(step + 1) / 100.0f;  // t for next step (matches ref)
    write_x(bh, wb0, wb1, fix96, bfhi(t1), xm);
    __syncthreads();

    short* tp = bx;
    bx = bh;
    bh = tp;
  }

  // ---- final store: fp32 x master -> out (B, 97, 16) ----
#pragma unroll
  for (int mtl = 0; mtl < 2; ++mtl)
#pragma unroll
    for (int r = 0; r < 4; ++r) {
      int q = (mt0 + mtl) * 16 + quad * 4 + r;
      if (q < QP1) out[(bglob * QP1 + q) * NC + col] = xm[mtl][r];
    }
}

extern "C" void kernel_launch(void* const* d_in, const int* in_sizes, int n_in,
                              void* d_out, int out_size, void* d_ws,
                              size_t ws_size, hipStream_t stream) {
  const float* series = (const float*)d_in[0];
  const float* rand_error = (const float*)d_in[1];
  const float* W1 = (const float*)d_in[2];
  const float* b1 = (const float*)d_in[3];
  const float* W2 = (const float*)d_in[4];
  const float* b2 = (const float*)d_in[5];
  const float* W3 = (const float*)d_in[6];
  const float* b3 = (const float*)d_in[7];
  float* out = (float*)d_out;

  dim3 grid(NB);  // 1024 WGs -> ~3 co-resident WGs/CU (barrier-stall overlap)
  dim3 block(NTHR);
  hipLaunchKernelGGL(arima_mfma_t, grid, block, 0, stream, series, rand_error,
                     W1, b1, W2, b2, W3, b3, out);
}